// Round 1
// 467.013 us; speedup vs baseline: 1.0106x; 1.0106x over previous
//
#include <hip/hip_runtime.h>
#include <math.h>

#define THREADS 256
#define BSHIFT 8
#define BSIZE 256   // nodes per bucket
#define NEB 512     // edge blocks for hist/place

typedef short short8 __attribute__((ext_vector_type(8)));
typedef float f32x4 __attribute__((ext_vector_type(4)));

// bf16 helpers (storage = ushort; RNE pack, exact unpack)
__device__ __forceinline__ unsigned short f2bf(float f) {
  unsigned u = __builtin_bit_cast(unsigned, f);
  return (unsigned short)((u + 0x7FFFu + ((u >> 16) & 1u)) >> 16);
}
__device__ __forceinline__ float bflo(unsigned u) {
  return __builtin_bit_cast(float, u << 16);
}
__device__ __forceinline__ float bfhi(unsigned u) {
  return __builtin_bit_cast(float, u & 0xFFFF0000u);
}
__device__ __forceinline__ unsigned pack2(float x, float y) {
  return (unsigned)f2bf(x) | ((unsigned)f2bf(y) << 16);
}

// unpack a uint4 (8 bf16 channels) and accumulate into a[0..7]
__device__ __forceinline__ void acc8(float* a, uint4 u) {
  a[0] += bflo(u.x); a[1] += bfhi(u.x);
  a[2] += bflo(u.y); a[3] += bfhi(u.y);
  a[4] += bflo(u.z); a[5] += bfhi(u.z);
  a[6] += bflo(u.w); a[7] += bfhi(u.w);
}

// ---------------- CSR build: two-pass local-offset binning ----------------

__global__ __launch_bounds__(256) void k_ehist(const int* __restrict__ dst,
                                               int* __restrict__ cnt_bm,
                                               int E, int chunk, int nbk) {
  __shared__ int h[1024];
  int blk = blockIdx.x, t = threadIdx.x;
  for (int i = t; i < nbk; i += 256) h[i] = 0;
  __syncthreads();
  int e0 = blk * chunk, e1 = min(e0 + chunk, E);
  for (int e = e0 + t; e < e1; e += 256) atomicAdd(&h[dst[e] >> BSHIFT], 1);
  __syncthreads();
  for (int i = t; i < nbk; i += 256) cnt_bm[(size_t)blk * nbk + i] = h[i];
}

__global__ __launch_bounds__(256) void k_bktscan(const int* __restrict__ cnt_bm,
                                                 int* __restrict__ locoff_tm,
                                                 int* __restrict__ bktot, int nbk) {
  int g = blockIdx.x, t = threadIdx.x;
  int c0 = cnt_bm[(size_t)(2 * t) * nbk + g];
  int c1 = cnt_bm[(size_t)(2 * t + 1) * nbk + g];
  __shared__ int sh[256];
  int s = c0 + c1;
  sh[t] = s;
  __syncthreads();
  for (int off = 1; off < 256; off <<= 1) {
    int v = (t >= off) ? sh[t - off] : 0;
    __syncthreads();
    if (t >= off) sh[t] += v;
    __syncthreads();
  }
  int excl = sh[t] - s;
  ((int2*)(locoff_tm + (size_t)g * NEB))[t] = make_int2(excl, excl + c0);
  if (t == 255) bktot[g] = sh[255];
}

__global__ __launch_bounds__(256) void k_topscan(const int* __restrict__ bktot,
                                                 int* __restrict__ bucket_base,
                                                 int nbk, int E,
                                                 int* __restrict__ row_ptr, int N) {
  __shared__ int sums[256];
  int t = threadIdx.x;
  int vals[4];
  int s = 0;
#pragma unroll
  for (int j = 0; j < 4; ++j) {
    int idx = t * 4 + j;
    vals[j] = (idx < nbk) ? bktot[idx] : 0;
    s += vals[j];
  }
  sums[t] = s;
  __syncthreads();
  for (int off = 1; off < 256; off <<= 1) {
    int v = (t >= off) ? sums[t - off] : 0;
    __syncthreads();
    if (t >= off) sums[t] += v;
    __syncthreads();
  }
  int run = sums[t] - s;
#pragma unroll
  for (int j = 0; j < 4; ++j) {
    int idx = t * 4 + j;
    if (idx < nbk) bucket_base[idx] = run;
    run += vals[j];
  }
  if (t == 0) { bucket_base[nbk] = E; row_ptr[N] = E; }
}

__global__ __launch_bounds__(256) void k_eplace(const int* __restrict__ src,
                                                const int* __restrict__ dst,
                                                const int* __restrict__ bucket_base,
                                                const int* __restrict__ locoff_tm,
                                                int* __restrict__ bedge,
                                                int E, int chunk, int nbk) {
  __shared__ int lptr[1024];
  int blk = blockIdx.x, t = threadIdx.x;
  for (int i = t; i < nbk; i += 256)
    lptr[i] = bucket_base[i] + locoff_tm[(size_t)i * NEB + blk];
  __syncthreads();
  int e0 = blk * chunk, e1 = min(e0 + chunk, E);
  for (int e = e0 + t; e < e1; e += 256) {
    int d = dst[e];
    int b = d >> BSHIFT;
    int p = atomicAdd(&lptr[b], 1);  // LDS atomic
    bedge[p] = (src[e] << 8) | (d & (BSIZE - 1));
  }
}

__global__ __launch_bounds__(256) void k_bcsr2(const int* __restrict__ bedge,
                                               const int* __restrict__ bucket_base,
                                               int* __restrict__ row_ptr,
                                               int* __restrict__ col, int N) {
  int g = blockIdx.x, t = threadIdx.x;
  int beg = bucket_base[g], end = bucket_base[g + 1];
  __shared__ int deg[BSIZE];
  __shared__ int sh[BSIZE];
  __shared__ int cur[BSIZE];
  deg[t] = 0;
  __syncthreads();
  for (int i = beg + t; i < end; i += 256)
    atomicAdd(&deg[bedge[i] & (BSIZE - 1)], 1);
  __syncthreads();
  int s = deg[t];
  sh[t] = s;
  __syncthreads();
  for (int off = 1; off < 256; off <<= 1) {
    int v = (t >= off) ? sh[t - off] : 0;
    __syncthreads();
    if (t >= off) sh[t] += v;
    __syncthreads();
  }
  int ex = beg + sh[t] - s;
  int node = g * BSIZE + t;
  if (node < N) row_ptr[node] = ex;
  cur[t] = ex;
  __syncthreads();
  for (int i = beg + t; i < end; i += 256) {
    int ed = bedge[i];
    int p = atomicAdd(&cur[ed & (BSIZE - 1)], 1);
    col[p] = ed >> 8;  // value < 2^25, positive
  }
}

// ---------------- fp32 -> bf16 convert (layer-0 X) ----------------
__global__ __launch_bounds__(256) void k_f2bf(const float4* __restrict__ in,
                                              ushort4* __restrict__ out, int n4) {
  int i = blockIdx.x * 256 + threadIdx.x;
  if (i < n4) {
    float4 v = in[i];
    ushort4 o;
    o.x = f2bf(v.x); o.y = f2bf(v.y); o.z = f2bf(v.z); o.w = f2bf(v.w);
    out[i] = o;
  }
}

// ---------------- W pre-swizzle into MFMA A-operand fragment layout ----------------
__global__ __launch_bounds__(256) void k_wswz(const float* __restrict__ Wl,
                                              const float* __restrict__ Wr,
                                              unsigned short* __restrict__ out) {
  int idx = blockIdx.x * 256 + threadIdx.x;  // 0..32767
  int j = idx & 7, lane = (idx >> 3) & 63, ct = (idx >> 9) & 15, ks = idx >> 13;
  int k = ks * 32 + (lane >> 4) * 8 + j;
  int c = ct * 16 + (lane & 15);
  float v = (c < 128) ? Wl[k * 128 + c] : Wr[k * 128 + (c - 128)];
  out[idx] = f2bf(v);
}

__global__ __launch_bounds__(256) void k_wswz40(const float* __restrict__ Wl,
                                                const float* __restrict__ Wr,
                                                unsigned short* __restrict__ out) {
  int idx = blockIdx.x * 256 + threadIdx.x;  // 0..10239
  int j = idx & 7, lane = (idx >> 3) & 63;
  int tile = idx >> 9;            // ks*5 + ct
  int ct = tile % 5, ks = tile / 5;
  int k = ks * 32 + (lane >> 4) * 8 + j;
  int c = ct * 16 + (lane & 15);
  float v = (c < 40) ? Wl[k * 40 + c] : ((c < 80) ? Wr[k * 40 + (c - 40)] : 0.f);
  out[idx] = f2bf(v);
}

// ---------------- MFMA dual GEMM, D=128, bf16 in/out, fp32 accum ----------------
// Round-12: BM=128 — each wave computes 2 row-groups (r, r+64) sharing every
// W-fragment load. W L2 traffic halves (was 4 waves x 64KB per 64-row block
// = ~400MB total). Grid halves to (N+127)/128.
__global__ __launch_bounds__(256) void gemm128_mfma(
    const unsigned short* __restrict__ Xb, const unsigned short* __restrict__ Wswz,
    const float* __restrict__ bias,
    unsigned short* __restrict__ outL, unsigned short* __restrict__ outR, int M) {
  int wave = threadIdx.x >> 6, lane = threadIdx.x & 63;
  int quad = lane >> 4, n16 = lane & 15;
  int rowA = blockIdx.x * 128 + wave * 16 + n16;
  int rowB = rowA + 64;
  int rA = min(rowA, M - 1), rB = min(rowB, M - 1);
  bool okA = rowA < M, okB = rowB < M;

  short8 xf[4], xg[4];
  const unsigned short* xpA = Xb + (size_t)rA * 128 + quad * 8;
  const unsigned short* xpB = Xb + (size_t)rB * 128 + quad * 8;
#pragma unroll
  for (int ks = 0; ks < 4; ++ks) {
    xf[ks] = *(const short8*)(xpA + ks * 32);
    xg[ks] = *(const short8*)(xpB + ks * 32);
  }

  size_t obA = (size_t)rowA * 128, obB = (size_t)rowB * 128;
#pragma unroll 2
  for (int ct = 0; ct < 16; ++ct) {
    f32x4 accA = {0.f, 0.f, 0.f, 0.f};
    f32x4 accB = {0.f, 0.f, 0.f, 0.f};
    const unsigned short* wp = Wswz + (size_t)(ct * 64 + lane) * 8;
#pragma unroll
    for (int ks = 0; ks < 4; ++ks) {
      short8 wf = *(const short8*)(wp + ks * 8192);
      accA = __builtin_amdgcn_mfma_f32_16x16x32_bf16(wf, xf[ks], accA, 0, 0, 0);
      accB = __builtin_amdgcn_mfma_f32_16x16x32_bf16(wf, xg[ks], accB, 0, 0, 0);
    }
    int colh = (ct & 7) * 16 + quad * 4;
    if (ct < 8) {
      if (okA) {
        ushort4 o;
        o.x = f2bf(accA[0]); o.y = f2bf(accA[1]); o.z = f2bf(accA[2]); o.w = f2bf(accA[3]);
        *(ushort4*)(outL + obA + colh) = o;
      }
      if (okB) {
        ushort4 o;
        o.x = f2bf(accB[0]); o.y = f2bf(accB[1]); o.z = f2bf(accB[2]); o.w = f2bf(accB[3]);
        *(ushort4*)(outL + obB + colh) = o;
      }
    } else {
      float4 bv = *(const float4*)(bias + colh);
      if (okA) {
        ushort4 o;
        o.x = f2bf(accA[0] + bv.x); o.y = f2bf(accA[1] + bv.y);
        o.z = f2bf(accA[2] + bv.z); o.w = f2bf(accA[3] + bv.w);
        *(ushort4*)(outR + obA + colh) = o;
      }
      if (okB) {
        ushort4 o;
        o.x = f2bf(accB[0] + bv.x); o.y = f2bf(accB[1] + bv.y);
        o.z = f2bf(accB[2] + bv.z); o.w = f2bf(accB[3] + bv.w);
        *(ushort4*)(outR + obB + colh) = o;
      }
    }
  }
}

// ---------------- MFMA dual GEMM, D=40 (layer 2) ----------------
__global__ __launch_bounds__(256) void gemm40_mfma(
    const unsigned short* __restrict__ Xb, const unsigned short* __restrict__ Wswz,
    const float* __restrict__ bias,
    unsigned short* __restrict__ tlb, float* __restrict__ tr, int M) {
  int wave = threadIdx.x >> 6, lane = threadIdx.x & 63;
  int quad = lane >> 4, n16 = lane & 15;
  int row = blockIdx.x * 64 + wave * 16 + n16;
  int row_ld = min(row, M - 1);
  bool ok = row < M;

  short8 xf[4];
  const unsigned short* xp = Xb + (size_t)row_ld * 128 + quad * 8;
#pragma unroll
  for (int ks = 0; ks < 4; ++ks) xf[ks] = *(const short8*)(xp + ks * 32);

#pragma unroll
  for (int ct = 0; ct < 5; ++ct) {
    f32x4 acc = {0.f, 0.f, 0.f, 0.f};
    const unsigned short* wp = Wswz + (size_t)(ct * 64 + lane) * 8;
#pragma unroll
    for (int ks = 0; ks < 4; ++ks) {
      short8 wf = *(const short8*)(wp + (size_t)ks * 5 * 64 * 8);
      acc = __builtin_amdgcn_mfma_f32_16x16x32_bf16(wf, xf[ks], acc, 0, 0, 0);
    }
    int cglob = ct * 16 + quad * 4;
    if (!ok) continue;
    if (cglob < 40) {
      ushort4 o;
      o.x = f2bf(acc[0]); o.y = f2bf(acc[1]); o.z = f2bf(acc[2]); o.w = f2bf(acc[3]);
      *(ushort4*)(tlb + (size_t)row * 64 + cglob) = o;
    } else {
      int c = cglob - 40;
      float4 bv = *(const float4*)(bias + c);
      float4 o;
      o.x = acc[0] + bv.x; o.y = acc[1] + bv.y;
      o.z = acc[2] + bv.z; o.w = acc[3] + bv.w;
      *(float4*)(tr + (size_t)row * 40 + c) = o;
    }
  }
}

// ---------------- aggregation D=128 (bf16), fused deg_inv+add+relu ----------------
// Round-13: latency-bound, not BW-bound (41% HBM path, VALU ~12% real).
// Restructure: quarter-wave uint4 gathers (16 lanes x 16B = one 256B row,
// 4 edges per VMEM instr, 16 edges in flight per round), col loads software-
// pipelined one round ahead, and the serial 2-edge tail replaced by one
// masked final round (clamped col index, cndmask-zeroed contribution).
// Serial memory rounds per wave: ~4 -> ~1.45.
__global__ __launch_bounds__(256) void agg128b(
    const unsigned short* __restrict__ xl, const unsigned short* __restrict__ xr,
    const int* __restrict__ row_ptr, const int* __restrict__ col,
    unsigned short* __restrict__ h, int Nn) {
  int wave = threadIdx.x >> 6;
  int lane = threadIdx.x & 63;
  int qw = lane >> 4;    // edge slot 0..3
  int l16 = lane & 15;   // uint4 index; channels 8*l16 .. 8*l16+7
  int n = blockIdx.x * 4 + wave;
  if (n >= Nn) return;
  int beg = row_ptr[n], end = row_ptr[n + 1];
  int deg = end - beg;
  const uint4* xq = (const uint4*)xl;
  float a0[8], a1[8];
#pragma unroll
  for (int j = 0; j < 8; ++j) { a0[j] = 0.f; a1[j] = 0.f; }
  int rounds = (deg + 15) >> 4;  // 16 edges per round
  if (rounds > 0) {
    int end1 = end - 1;
    int e = beg + qw;
    int c0 = col[min(e, end1)];
    int c1 = col[min(e + 4, end1)];
    int c2 = col[min(e + 8, end1)];
    int c3 = col[min(e + 12, end1)];
    for (int it = rounds - 1; it > 0; --it) {
      // gathers first (issue before next-round col prefetch so the wait
      // before acc leaves the col loads outstanding)
      uint4 u0 = xq[(size_t)c0 * 16 + l16];
      uint4 u1 = xq[(size_t)c1 * 16 + l16];
      uint4 u2 = xq[(size_t)c2 * 16 + l16];
      uint4 u3 = xq[(size_t)c3 * 16 + l16];
      int en = e + 16;
      int cn0 = col[min(en, end1)];
      int cn1 = col[min(en + 4, end1)];
      int cn2 = col[min(en + 8, end1)];
      int cn3 = col[min(en + 12, end1)];
      acc8(a0, u0); acc8(a1, u1); acc8(a0, u2); acc8(a1, u3);
      c0 = cn0; c1 = cn1; c2 = cn2; c3 = cn3; e = en;
    }
    // final (possibly partial) round: clamped loads, masked accumulate
    uint4 u0 = xq[(size_t)c0 * 16 + l16];
    uint4 u1 = xq[(size_t)c1 * 16 + l16];
    uint4 u2 = xq[(size_t)c2 * 16 + l16];
    uint4 u3 = xq[(size_t)c3 * 16 + l16];
    uint4 z = make_uint4(0u, 0u, 0u, 0u);
    if (e >= end) u0 = z;
    if (e + 4 >= end) u1 = z;
    if (e + 8 >= end) u2 = z;
    if (e + 12 >= end) u3 = z;
    acc8(a0, u0); acc8(a1, u1); acc8(a0, u2); acc8(a1, u3);
  }
  float s[8];
#pragma unroll
  for (int j = 0; j < 8; ++j) {
    float t = a0[j] + a1[j];
    t += __shfl_xor(t, 16);
    t += __shfl_xor(t, 32);
    s[j] = t;
  }
  if (qw == 0) {
    float di = 1.0f / (float)max(deg, 1);
    uint4 r = ((const uint4*)xr)[(size_t)n * 16 + l16];
    float rb[8] = {bflo(r.x), bfhi(r.x), bflo(r.y), bfhi(r.y),
                   bflo(r.z), bfhi(r.z), bflo(r.w), bfhi(r.w)};
    float o[8];
#pragma unroll
    for (int j = 0; j < 8; ++j) o[j] = fmaxf(fmaf(s[j], di, rb[j]), 0.f);
    uint4 w;
    w.x = pack2(o[0], o[1]);
    w.y = pack2(o[2], o[3]);
    w.z = pack2(o[4], o[5]);
    w.w = pack2(o[6], o[7]);
    ((uint4*)h)[(size_t)n * 16 + l16] = w;
  }
}

// ---------------- aggregation D=40 (bf16 padded-64) + log_softmax ----------------
// Round-13: same restructure as agg128b — pipelined col loads + masked final
// round replace the serial stride-8 tail. Eighth-wave uint4 layout kept.
// Pad channels 40..63 are read as poison (memset dropped) but provably
// discarded: invalid lanes contribute -INF to max and 0 to the exp-sum.
__global__ __launch_bounds__(256) void agg40_lsm(
    const unsigned short* __restrict__ tlb, const float* __restrict__ tr,
    const int* __restrict__ row_ptr, const int* __restrict__ col,
    float* __restrict__ out, int Nn) {
  int wave = threadIdx.x >> 6;
  int lane = threadIdx.x & 63;
  int ew = lane >> 3;    // edge slot 0..7
  int l8 = lane & 7;     // uint4 index; channels 8*l8 .. 8*l8+7
  int n = blockIdx.x * 4 + wave;
  if (n >= Nn) return;
  int beg = row_ptr[n], end = row_ptr[n + 1];
  int deg = end - beg;
  const uint4* tlq = (const uint4*)tlb;
  float a0[8], a1[8];
#pragma unroll
  for (int j = 0; j < 8; ++j) { a0[j] = 0.f; a1[j] = 0.f; }
  int rounds = (deg + 15) >> 4;  // 16 edges per round
  if (rounds > 0) {
    int end1 = end - 1;
    int e = beg + ew;
    int c0 = col[min(e, end1)];
    int c1 = col[min(e + 8, end1)];
    for (int it = rounds - 1; it > 0; --it) {
      uint4 u0 = tlq[(size_t)c0 * 8 + l8];
      uint4 u1 = tlq[(size_t)c1 * 8 + l8];
      int en = e + 16;
      int cn0 = col[min(en, end1)];
      int cn1 = col[min(en + 8, end1)];
      acc8(a0, u0); acc8(a1, u1);
      c0 = cn0; c1 = cn1; e = en;
    }
    uint4 u0 = tlq[(size_t)c0 * 8 + l8];
    uint4 u1 = tlq[(size_t)c1 * 8 + l8];
    uint4 z = make_uint4(0u, 0u, 0u, 0u);
    if (e >= end) u0 = z;
    if (e + 8 >= end) u1 = z;
    acc8(a0, u0); acc8(a1, u1);
  }
  float v[8];
#pragma unroll
  for (int j = 0; j < 8; ++j) {
    float t = a0[j] + a1[j];
    t += __shfl_xor(t, 32);
    t += __shfl_xor(t, 16);
    t += __shfl_xor(t, 8);
    v[j] = t;
  }
  bool valid = l8 < 5;  // channels 8*l8..8*l8+7 < 40
  float di = 1.0f / (float)max(deg, 1);
  float4 r0 = valid ? *(const float4*)(tr + (size_t)n * 40 + 8 * l8)
                    : make_float4(0.f, 0.f, 0.f, 0.f);
  float4 r1 = valid ? *(const float4*)(tr + (size_t)n * 40 + 8 * l8 + 4)
                    : make_float4(0.f, 0.f, 0.f, 0.f);
  float rb[8] = {r0.x, r0.y, r0.z, r0.w, r1.x, r1.y, r1.z, r1.w};
  float vv[8];
#pragma unroll
  for (int j = 0; j < 8; ++j) vv[j] = valid ? fmaf(v[j], di, rb[j]) : -INFINITY;
  float m = vv[0];
#pragma unroll
  for (int j = 1; j < 8; ++j) m = fmaxf(m, vv[j]);
#pragma unroll
  for (int off = 4; off; off >>= 1) m = fmaxf(m, __shfl_xor(m, off));
  float ex = 0.f;
  if (valid) {
#pragma unroll
    for (int j = 0; j < 8; ++j) ex += expf(vv[j] - m);
  }
  float ssum = ex;
#pragma unroll
  for (int off = 4; off; off >>= 1) ssum += __shfl_xor(ssum, off);
  float lg = logf(ssum);
  if (ew == 0 && valid) {
    float4 o0, o1;
    o0.x = (vv[0] - m) - lg; o0.y = (vv[1] - m) - lg;
    o0.z = (vv[2] - m) - lg; o0.w = (vv[3] - m) - lg;
    o1.x = (vv[4] - m) - lg; o1.y = (vv[5] - m) - lg;
    o1.z = (vv[6] - m) - lg; o1.w = (vv[7] - m) - lg;
    *(float4*)(out + (size_t)n * 40 + 8 * l8) = o0;
    *(float4*)(out + (size_t)n * 40 + 8 * l8 + 4) = o1;
  }
}

// ---------------- launcher ----------------

extern "C" void kernel_launch(void* const* d_in, const int* in_sizes, int n_in,
                              void* d_out, int out_size, void* d_ws, size_t ws_size,
                              hipStream_t stream) {
  const float* x   = (const float*)d_in[0];
  const int*   ei  = (const int*)d_in[1];
  const float* Wl0 = (const float*)d_in[2];
  const float* Wr0 = (const float*)d_in[3];
  const float* b0  = (const float*)d_in[4];
  const float* Wl1 = (const float*)d_in[5];
  const float* Wr1 = (const float*)d_in[6];
  const float* b1  = (const float*)d_in[7];
  const float* Wl2 = (const float*)d_in[8];
  const float* Wr2 = (const float*)d_in[9];
  const float* b2  = (const float*)d_in[10];

  int N = in_sizes[0] / 128;
  int E = in_sizes[1] / 2;
  const int* src = ei;
  const int* dst = ei + E;
  int nbk = (N + BSIZE - 1) / BSIZE;       // 391 buckets of 256 nodes
  int chunk = (E + NEB - 1) / NEB;         // edges per hist/place block

  char* ws = (char*)d_ws;
  size_t off = 0;
  auto alloc = [&](size_t bytes) -> void* {
    void* p = ws + off;
    off += (bytes + 255) & ~(size_t)255;
    return p;
  };
  unsigned short* xb  = (unsigned short*)alloc((size_t)N * 128 * 2);
  unsigned short* gA  = (unsigned short*)alloc((size_t)N * 128 * 2);
  unsigned short* gB  = (unsigned short*)alloc((size_t)N * 128 * 2);
  unsigned short* hC  = (unsigned short*)alloc((size_t)N * 128 * 2);
  unsigned short* tlb = (unsigned short*)alloc((size_t)N * 64 * 2);
  float* tr           = (float*)alloc((size_t)N * 40 * 4);
  int* row_ptr  = (int*)alloc((size_t)(N + 1) * 4);
  int* col      = (int*)alloc((size_t)E * 4);
  int* bedge    = (int*)alloc((size_t)E * 4);   // packed (src<<8)|(dst&255)
  int* cnt_bm   = (int*)alloc((size_t)NEB * nbk * 4);
  int* locoff   = (int*)alloc((size_t)nbk * NEB * 4);
  int* bktot    = (int*)alloc((size_t)nbk * 4);
  int* bbase    = (int*)alloc((size_t)(nbk + 1) * 4);
  unsigned short* wswz0 = (unsigned short*)alloc(32768 * 2);
  unsigned short* wswz1 = (unsigned short*)alloc(32768 * 2);
  unsigned short* wswz2 = (unsigned short*)alloc(10240 * 2);
  (void)ws_size; (void)n_in; (void)out_size;

  // CSR build (no global atomics; all writes block-local or exact-offset)
  k_ehist<<<NEB, 256, 0, stream>>>(dst, cnt_bm, E, chunk, nbk);
  k_bktscan<<<nbk, 256, 0, stream>>>(cnt_bm, locoff, bktot, nbk);
  k_topscan<<<1, 256, 0, stream>>>(bktot, bbase, nbk, E, row_ptr, N);
  k_eplace<<<NEB, 256, 0, stream>>>(src, dst, bbase, locoff, bedge, E, chunk, nbk);
  k_bcsr2<<<nbk, 256, 0, stream>>>(bedge, bbase, row_ptr, col, N);

  int n4 = N * 32;
  k_f2bf<<<(n4 + 255) / 256, 256, 0, stream>>>((const float4*)x, (ushort4*)xb, n4);
  k_wswz<<<128, 256, 0, stream>>>(Wl0, Wr0, wswz0);
  k_wswz<<<128, 256, 0, stream>>>(Wl1, Wr1, wswz1);
  k_wswz40<<<40, 256, 0, stream>>>(Wl2, Wr2, wswz2);

  int gg128 = (N + 127) / 128;
  int gg = (N + 63) / 64;
  int nb = (N + 3) / 4;

  // layer 0
  gemm128_mfma<<<gg128, 256, 0, stream>>>(xb, wswz0, b0, gA, gB, N);
  agg128b<<<nb, 256, 0, stream>>>(gA, gB, row_ptr, col, hC, N);
  // layer 1
  gemm128_mfma<<<gg128, 256, 0, stream>>>(hC, wswz1, b1, gA, gB, N);
  agg128b<<<nb, 256, 0, stream>>>(gA, gB, row_ptr, col, hC, N);
  // layer 2 (40-dim) + log_softmax
  gemm40_mfma<<<gg, 256, 0, stream>>>(hC, wswz2, b2, tlb, tr, N);
  agg40_lsm<<<nb, 256, 0, stream>>>(tlb, tr, row_ptr, col, (float*)d_out, N);
}

// Round 2
// 446.663 us; speedup vs baseline: 1.0567x; 1.0456x over previous
//
#include <hip/hip_runtime.h>
#include <math.h>

#define THREADS 256
#define BSHIFT 8
#define BSIZE 256   // nodes per bucket
#define NEB 512     // edge blocks for hist/place

typedef short short8 __attribute__((ext_vector_type(8)));
typedef float f32x4 __attribute__((ext_vector_type(4)));

// bf16 helpers (storage = ushort; RNE pack, exact unpack)
__device__ __forceinline__ unsigned short f2bf(float f) {
  unsigned u = __builtin_bit_cast(unsigned, f);
  return (unsigned short)((u + 0x7FFFu + ((u >> 16) & 1u)) >> 16);
}
__device__ __forceinline__ float bflo(unsigned u) {
  return __builtin_bit_cast(float, u << 16);
}
__device__ __forceinline__ float bfhi(unsigned u) {
  return __builtin_bit_cast(float, u & 0xFFFF0000u);
}
__device__ __forceinline__ unsigned pack2(float x, float y) {
  return (unsigned)f2bf(x) | ((unsigned)f2bf(y) << 16);
}

// unpack a uint4 (8 bf16 channels) and accumulate into a[0..7]
__device__ __forceinline__ void acc8(float* a, uint4 u) {
  a[0] += bflo(u.x); a[1] += bfhi(u.x);
  a[2] += bflo(u.y); a[3] += bfhi(u.y);
  a[4] += bflo(u.z); a[5] += bfhi(u.z);
  a[6] += bflo(u.w); a[7] += bfhi(u.w);
}

// ---------------- CSR build: two-pass local-offset binning ----------------

__global__ __launch_bounds__(256) void k_ehist(const int* __restrict__ dst,
                                               int* __restrict__ cnt_bm,
                                               int E, int chunk, int nbk) {
  __shared__ int h[1024];
  int blk = blockIdx.x, t = threadIdx.x;
  for (int i = t; i < nbk; i += 256) h[i] = 0;
  __syncthreads();
  int e0 = blk * chunk, e1 = min(e0 + chunk, E);
  for (int e = e0 + t; e < e1; e += 256) atomicAdd(&h[dst[e] >> BSHIFT], 1);
  __syncthreads();
  for (int i = t; i < nbk; i += 256) cnt_bm[(size_t)blk * nbk + i] = h[i];
}

__global__ __launch_bounds__(256) void k_bktscan(const int* __restrict__ cnt_bm,
                                                 int* __restrict__ locoff_tm,
                                                 int* __restrict__ bktot, int nbk) {
  int g = blockIdx.x, t = threadIdx.x;
  int c0 = cnt_bm[(size_t)(2 * t) * nbk + g];
  int c1 = cnt_bm[(size_t)(2 * t + 1) * nbk + g];
  __shared__ int sh[256];
  int s = c0 + c1;
  sh[t] = s;
  __syncthreads();
  for (int off = 1; off < 256; off <<= 1) {
    int v = (t >= off) ? sh[t - off] : 0;
    __syncthreads();
    if (t >= off) sh[t] += v;
    __syncthreads();
  }
  int excl = sh[t] - s;
  ((int2*)(locoff_tm + (size_t)g * NEB))[t] = make_int2(excl, excl + c0);
  if (t == 255) bktot[g] = sh[255];
}

__global__ __launch_bounds__(256) void k_topscan(const int* __restrict__ bktot,
                                                 int* __restrict__ bucket_base,
                                                 int nbk, int E,
                                                 int* __restrict__ row_ptr, int N) {
  __shared__ int sums[256];
  int t = threadIdx.x;
  int vals[4];
  int s = 0;
#pragma unroll
  for (int j = 0; j < 4; ++j) {
    int idx = t * 4 + j;
    vals[j] = (idx < nbk) ? bktot[idx] : 0;
    s += vals[j];
  }
  sums[t] = s;
  __syncthreads();
  for (int off = 1; off < 256; off <<= 1) {
    int v = (t >= off) ? sums[t - off] : 0;
    __syncthreads();
    if (t >= off) sums[t] += v;
    __syncthreads();
  }
  int run = sums[t] - s;
#pragma unroll
  for (int j = 0; j < 4; ++j) {
    int idx = t * 4 + j;
    if (idx < nbk) bucket_base[idx] = run;
    run += vals[j];
  }
  if (t == 0) { bucket_base[nbk] = E; row_ptr[N] = E; }
}

__global__ __launch_bounds__(256) void k_eplace(const int* __restrict__ src,
                                                const int* __restrict__ dst,
                                                const int* __restrict__ bucket_base,
                                                const int* __restrict__ locoff_tm,
                                                int* __restrict__ bedge,
                                                int E, int chunk, int nbk) {
  __shared__ int lptr[1024];
  int blk = blockIdx.x, t = threadIdx.x;
  for (int i = t; i < nbk; i += 256)
    lptr[i] = bucket_base[i] + locoff_tm[(size_t)i * NEB + blk];
  __syncthreads();
  int e0 = blk * chunk, e1 = min(e0 + chunk, E);
  for (int e = e0 + t; e < e1; e += 256) {
    int d = dst[e];
    int b = d >> BSHIFT;
    int p = atomicAdd(&lptr[b], 1);  // LDS atomic
    bedge[p] = (src[e] << 8) | (d & (BSIZE - 1));
  }
}

__global__ __launch_bounds__(256) void k_bcsr2(const int* __restrict__ bedge,
                                               const int* __restrict__ bucket_base,
                                               int* __restrict__ row_ptr,
                                               int* __restrict__ col, int N) {
  int g = blockIdx.x, t = threadIdx.x;
  int beg = bucket_base[g], end = bucket_base[g + 1];
  __shared__ int deg[BSIZE];
  __shared__ int sh[BSIZE];
  __shared__ int cur[BSIZE];
  deg[t] = 0;
  __syncthreads();
  for (int i = beg + t; i < end; i += 256)
    atomicAdd(&deg[bedge[i] & (BSIZE - 1)], 1);
  __syncthreads();
  int s = deg[t];
  sh[t] = s;
  __syncthreads();
  for (int off = 1; off < 256; off <<= 1) {
    int v = (t >= off) ? sh[t - off] : 0;
    __syncthreads();
    if (t >= off) sh[t] += v;
    __syncthreads();
  }
  int ex = beg + sh[t] - s;
  int node = g * BSIZE + t;
  if (node < N) row_ptr[node] = ex;
  cur[t] = ex;
  __syncthreads();
  for (int i = beg + t; i < end; i += 256) {
    int ed = bedge[i];
    int p = atomicAdd(&cur[ed & (BSIZE - 1)], 1);
    col[p] = ed >> 8;  // value < 2^25, positive
  }
}

// ---------------- W pre-swizzle (all 3 layers fused in one dispatch) ----------------
// blocks [0,128): layer0 -> out0 ; [128,256): layer1 -> out1 ; [256,296): layer2 -> out2
__global__ __launch_bounds__(256) void k_wswz_all(
    const float* __restrict__ Wl0, const float* __restrict__ Wr0,
    const float* __restrict__ Wl1, const float* __restrict__ Wr1,
    const float* __restrict__ Wl2, const float* __restrict__ Wr2,
    unsigned short* __restrict__ out0, unsigned short* __restrict__ out1,
    unsigned short* __restrict__ out2) {
  int b = blockIdx.x, t = threadIdx.x;
  if (b < 256) {
    const float* Wl = (b < 128) ? Wl0 : Wl1;
    const float* Wr = (b < 128) ? Wr0 : Wr1;
    unsigned short* out = (b < 128) ? out0 : out1;
    int idx = (b & 127) * 256 + t;  // 0..32767
    int j = idx & 7, lane = (idx >> 3) & 63, ct = (idx >> 9) & 15, ks = idx >> 13;
    int k = ks * 32 + (lane >> 4) * 8 + j;
    int c = ct * 16 + (lane & 15);
    float v = (c < 128) ? Wl[k * 128 + c] : Wr[k * 128 + (c - 128)];
    out[idx] = f2bf(v);
  } else {
    int idx = (b - 256) * 256 + t;  // 0..10239
    int j = idx & 7, lane = (idx >> 3) & 63;
    int tile = idx >> 9;            // ks*5 + ct
    int ct = tile % 5, ks = tile / 5;
    int k = ks * 32 + (lane >> 4) * 8 + j;
    int c = ct * 16 + (lane & 15);
    float v = (c < 40) ? Wl2[k * 40 + c] : ((c < 80) ? Wr2[k * 40 + (c - 40)] : 0.f);
    out2[idx] = f2bf(v);
  }
}

// ---------------- MFMA dual GEMM, D=128, layer 0: fp32 X in, bf16 out ----------------
// Round-14: f2bf pass folded in — reads fp32 X once (51.2MB) instead of the
// separate convert pass (51.2R + 25.6W) + bf16 reread (25.6R). Net −51MB.
__global__ __launch_bounds__(256) void gemm128_mfma_x32(
    const float* __restrict__ X, const unsigned short* __restrict__ Wswz,
    const float* __restrict__ bias,
    unsigned short* __restrict__ outL, unsigned short* __restrict__ outR, int M) {
  int wave = threadIdx.x >> 6, lane = threadIdx.x & 63;
  int quad = lane >> 4, n16 = lane & 15;
  int rowA = blockIdx.x * 128 + wave * 16 + n16;
  int rowB = rowA + 64;
  int rA = min(rowA, M - 1), rB = min(rowB, M - 1);
  bool okA = rowA < M, okB = rowB < M;

  short8 xf[4], xg[4];
  const float* xpA = X + (size_t)rA * 128 + quad * 8;
  const float* xpB = X + (size_t)rB * 128 + quad * 8;
#pragma unroll
  for (int ks = 0; ks < 4; ++ks) {
    float4 a0 = *(const float4*)(xpA + ks * 32);
    float4 a1 = *(const float4*)(xpA + ks * 32 + 4);
    float4 b0 = *(const float4*)(xpB + ks * 32);
    float4 b1 = *(const float4*)(xpB + ks * 32 + 4);
    short8 f, g;
    f[0] = (short)f2bf(a0.x); f[1] = (short)f2bf(a0.y);
    f[2] = (short)f2bf(a0.z); f[3] = (short)f2bf(a0.w);
    f[4] = (short)f2bf(a1.x); f[5] = (short)f2bf(a1.y);
    f[6] = (short)f2bf(a1.z); f[7] = (short)f2bf(a1.w);
    g[0] = (short)f2bf(b0.x); g[1] = (short)f2bf(b0.y);
    g[2] = (short)f2bf(b0.z); g[3] = (short)f2bf(b0.w);
    g[4] = (short)f2bf(b1.x); g[5] = (short)f2bf(b1.y);
    g[6] = (short)f2bf(b1.z); g[7] = (short)f2bf(b1.w);
    xf[ks] = f;
    xg[ks] = g;
  }

  size_t obA = (size_t)rowA * 128, obB = (size_t)rowB * 128;
#pragma unroll 2
  for (int ct = 0; ct < 16; ++ct) {
    f32x4 accA = {0.f, 0.f, 0.f, 0.f};
    f32x4 accB = {0.f, 0.f, 0.f, 0.f};
    const unsigned short* wp = Wswz + (size_t)(ct * 64 + lane) * 8;
#pragma unroll
    for (int ks = 0; ks < 4; ++ks) {
      short8 wf = *(const short8*)(wp + ks * 8192);
      accA = __builtin_amdgcn_mfma_f32_16x16x32_bf16(wf, xf[ks], accA, 0, 0, 0);
      accB = __builtin_amdgcn_mfma_f32_16x16x32_bf16(wf, xg[ks], accB, 0, 0, 0);
    }
    int colh = (ct & 7) * 16 + quad * 4;
    if (ct < 8) {
      if (okA) {
        ushort4 o;
        o.x = f2bf(accA[0]); o.y = f2bf(accA[1]); o.z = f2bf(accA[2]); o.w = f2bf(accA[3]);
        *(ushort4*)(outL + obA + colh) = o;
      }
      if (okB) {
        ushort4 o;
        o.x = f2bf(accB[0]); o.y = f2bf(accB[1]); o.z = f2bf(accB[2]); o.w = f2bf(accB[3]);
        *(ushort4*)(outL + obB + colh) = o;
      }
    } else {
      float4 bv = *(const float4*)(bias + colh);
      if (okA) {
        ushort4 o;
        o.x = f2bf(accA[0] + bv.x); o.y = f2bf(accA[1] + bv.y);
        o.z = f2bf(accA[2] + bv.z); o.w = f2bf(accA[3] + bv.w);
        *(ushort4*)(outR + obA + colh) = o;
      }
      if (okB) {
        ushort4 o;
        o.x = f2bf(accB[0] + bv.x); o.y = f2bf(accB[1] + bv.y);
        o.z = f2bf(accB[2] + bv.z); o.w = f2bf(accB[3] + bv.w);
        *(ushort4*)(outR + obB + colh) = o;
      }
    }
  }
}

// ---------------- MFMA dual GEMM, D=128, bf16 in/out (layers 1) ----------------
__global__ __launch_bounds__(256) void gemm128_mfma(
    const unsigned short* __restrict__ Xb, const unsigned short* __restrict__ Wswz,
    const float* __restrict__ bias,
    unsigned short* __restrict__ outL, unsigned short* __restrict__ outR, int M) {
  int wave = threadIdx.x >> 6, lane = threadIdx.x & 63;
  int quad = lane >> 4, n16 = lane & 15;
  int rowA = blockIdx.x * 128 + wave * 16 + n16;
  int rowB = rowA + 64;
  int rA = min(rowA, M - 1), rB = min(rowB, M - 1);
  bool okA = rowA < M, okB = rowB < M;

  short8 xf[4], xg[4];
  const unsigned short* xpA = Xb + (size_t)rA * 128 + quad * 8;
  const unsigned short* xpB = Xb + (size_t)rB * 128 + quad * 8;
#pragma unroll
  for (int ks = 0; ks < 4; ++ks) {
    xf[ks] = *(const short8*)(xpA + ks * 32);
    xg[ks] = *(const short8*)(xpB + ks * 32);
  }

  size_t obA = (size_t)rowA * 128, obB = (size_t)rowB * 128;
#pragma unroll 2
  for (int ct = 0; ct < 16; ++ct) {
    f32x4 accA = {0.f, 0.f, 0.f, 0.f};
    f32x4 accB = {0.f, 0.f, 0.f, 0.f};
    const unsigned short* wp = Wswz + (size_t)(ct * 64 + lane) * 8;
#pragma unroll
    for (int ks = 0; ks < 4; ++ks) {
      short8 wf = *(const short8*)(wp + ks * 8192);
      accA = __builtin_amdgcn_mfma_f32_16x16x32_bf16(wf, xf[ks], accA, 0, 0, 0);
      accB = __builtin_amdgcn_mfma_f32_16x16x32_bf16(wf, xg[ks], accB, 0, 0, 0);
    }
    int colh = (ct & 7) * 16 + quad * 4;
    if (ct < 8) {
      if (okA) {
        ushort4 o;
        o.x = f2bf(accA[0]); o.y = f2bf(accA[1]); o.z = f2bf(accA[2]); o.w = f2bf(accA[3]);
        *(ushort4*)(outL + obA + colh) = o;
      }
      if (okB) {
        ushort4 o;
        o.x = f2bf(accB[0]); o.y = f2bf(accB[1]); o.z = f2bf(accB[2]); o.w = f2bf(accB[3]);
        *(ushort4*)(outL + obB + colh) = o;
      }
    } else {
      float4 bv = *(const float4*)(bias + colh);
      if (okA) {
        ushort4 o;
        o.x = f2bf(accA[0] + bv.x); o.y = f2bf(accA[1] + bv.y);
        o.z = f2bf(accA[2] + bv.z); o.w = f2bf(accA[3] + bv.w);
        *(ushort4*)(outR + obA + colh) = o;
      }
      if (okB) {
        ushort4 o;
        o.x = f2bf(accB[0] + bv.x); o.y = f2bf(accB[1] + bv.y);
        o.z = f2bf(accB[2] + bv.z); o.w = f2bf(accB[3] + bv.w);
        *(ushort4*)(outR + obB + colh) = o;
      }
    }
  }
}

// ---------------- MFMA dual GEMM, D=40 (layer 2) ----------------
__global__ __launch_bounds__(256) void gemm40_mfma(
    const unsigned short* __restrict__ Xb, const unsigned short* __restrict__ Wswz,
    const float* __restrict__ bias,
    unsigned short* __restrict__ tlb, float* __restrict__ tr, int M) {
  int wave = threadIdx.x >> 6, lane = threadIdx.x & 63;
  int quad = lane >> 4, n16 = lane & 15;
  int row = blockIdx.x * 64 + wave * 16 + n16;
  int row_ld = min(row, M - 1);
  bool ok = row < M;

  short8 xf[4];
  const unsigned short* xp = Xb + (size_t)row_ld * 128 + quad * 8;
#pragma unroll
  for (int ks = 0; ks < 4; ++ks) xf[ks] = *(const short8*)(xp + ks * 32);

#pragma unroll
  for (int ct = 0; ct < 5; ++ct) {
    f32x4 acc = {0.f, 0.f, 0.f, 0.f};
    const unsigned short* wp = Wswz + (size_t)(ct * 64 + lane) * 8;
#pragma unroll
    for (int ks = 0; ks < 4; ++ks) {
      short8 wf = *(const short8*)(wp + (size_t)ks * 5 * 64 * 8);
      acc = __builtin_amdgcn_mfma_f32_16x16x32_bf16(wf, xf[ks], acc, 0, 0, 0);
    }
    int cglob = ct * 16 + quad * 4;
    if (!ok) continue;
    if (cglob < 40) {
      ushort4 o;
      o.x = f2bf(acc[0]); o.y = f2bf(acc[1]); o.z = f2bf(acc[2]); o.w = f2bf(acc[3]);
      *(ushort4*)(tlb + (size_t)row * 64 + cglob) = o;
    } else {
      int c = cglob - 40;
      float4 bv = *(const float4*)(bias + c);
      float4 o;
      o.x = acc[0] + bv.x; o.y = acc[1] + bv.y;
      o.z = acc[2] + bv.z; o.w = acc[3] + bv.w;
      *(float4*)(tr + (size_t)row * 40 + c) = o;
    }
  }
}

// ---------------- aggregation D=128 (bf16), fused deg_inv+add+relu ----------------
// Round-14: reverted to the round-11 pair-wave uint2 structure (67.5us, 28
// VGPR). Round-13's quarter-wave/pipelined variant measured 69.1us at equal
// FETCH_SIZE (192MB) — the kernel is at the structural L2-miss floor (each
// XCD fetches the used 25.6MB table once: ~177MB bound) served at ~3.2TB/s;
// extra MLP cannot reduce mandatory miss bytes.
__global__ __launch_bounds__(256) void agg128b(
    const unsigned short* __restrict__ xl, const unsigned short* __restrict__ xr,
    const int* __restrict__ row_ptr, const int* __restrict__ col,
    unsigned short* __restrict__ h, int Nn) {
  int wave = threadIdx.x >> 6;
  int lane = threadIdx.x & 63;
  int pair = lane >> 5;
  int l32 = lane & 31;
  int n = blockIdx.x * 4 + wave;
  if (n >= Nn) return;
  int beg = row_ptr[n], end = row_ptr[n + 1];
  int deg = end - beg;
  const uint2* xlq = (const uint2*)xl;
  float a0x = 0.f, a0y = 0.f, a0z = 0.f, a0w = 0.f;
  float a1x = 0.f, a1y = 0.f, a1z = 0.f, a1w = 0.f;
  float a2x = 0.f, a2y = 0.f, a2z = 0.f, a2w = 0.f;
  float a3x = 0.f, a3y = 0.f, a3z = 0.f, a3w = 0.f;
  int e = beg + pair;
  for (int it = deg >> 3; it > 0; --it, e += 8) {
    uint2 u0 = xlq[(size_t)col[e]     * 32 + l32];
    uint2 u1 = xlq[(size_t)col[e + 2] * 32 + l32];
    uint2 u2 = xlq[(size_t)col[e + 4] * 32 + l32];
    uint2 u3 = xlq[(size_t)col[e + 6] * 32 + l32];
    a0x += bflo(u0.x); a0y += bfhi(u0.x); a0z += bflo(u0.y); a0w += bfhi(u0.y);
    a1x += bflo(u1.x); a1y += bfhi(u1.x); a1z += bflo(u1.y); a1w += bfhi(u1.y);
    a2x += bflo(u2.x); a2y += bfhi(u2.x); a2z += bflo(u2.y); a2w += bfhi(u2.y);
    a3x += bflo(u3.x); a3y += bfhi(u3.x); a3z += bflo(u3.y); a3w += bfhi(u3.y);
  }
  for (; e < end; e += 2) {
    uint2 u = xlq[(size_t)col[e] * 32 + l32];
    a0x += bflo(u.x); a0y += bfhi(u.x); a0z += bflo(u.y); a0w += bfhi(u.y);
  }
  float ax = (a0x + a1x) + (a2x + a3x);
  float ay = (a0y + a1y) + (a2y + a3y);
  float az = (a0z + a1z) + (a2z + a3z);
  float aw = (a0w + a1w) + (a2w + a3w);
  ax += __shfl_xor(ax, 32);
  ay += __shfl_xor(ay, 32);
  az += __shfl_xor(az, 32);
  aw += __shfl_xor(aw, 32);
  if (pair == 0) {
    float di = 1.0f / (float)max(deg, 1);
    uint2 r = ((const uint2*)xr)[(size_t)n * 32 + l32];
    float ox = fmaxf(fmaf(ax, di, bflo(r.x)), 0.f);
    float oy = fmaxf(fmaf(ay, di, bfhi(r.x)), 0.f);
    float oz = fmaxf(fmaf(az, di, bflo(r.y)), 0.f);
    float ow = fmaxf(fmaf(aw, di, bfhi(r.y)), 0.f);
    uint2 o;
    o.x = pack2(ox, oy);
    o.y = pack2(oz, ow);
    ((uint2*)h)[(size_t)n * 32 + l32] = o;
  }
}

// ---------------- aggregation D=40 (bf16 padded-64) + log_softmax ----------------
// Round-13 structure kept (measured ~6-8us better than round-12): pipelined
// col loads + masked final round replace the serial stride-8 tail.
// Pad channels 40..63 are read as poison (memset dropped) but provably
// discarded: invalid lanes contribute -INF to max and 0 to the exp-sum.
__global__ __launch_bounds__(256) void agg40_lsm(
    const unsigned short* __restrict__ tlb, const float* __restrict__ tr,
    const int* __restrict__ row_ptr, const int* __restrict__ col,
    float* __restrict__ out, int Nn) {
  int wave = threadIdx.x >> 6;
  int lane = threadIdx.x & 63;
  int ew = lane >> 3;    // edge slot 0..7
  int l8 = lane & 7;     // uint4 index; channels 8*l8 .. 8*l8+7
  int n = blockIdx.x * 4 + wave;
  if (n >= Nn) return;
  int beg = row_ptr[n], end = row_ptr[n + 1];
  int deg = end - beg;
  const uint4* tlq = (const uint4*)tlb;
  float a0[8], a1[8];
#pragma unroll
  for (int j = 0; j < 8; ++j) { a0[j] = 0.f; a1[j] = 0.f; }
  int rounds = (deg + 15) >> 4;  // 16 edges per round
  if (rounds > 0) {
    int end1 = end - 1;
    int e = beg + ew;
    int c0 = col[min(e, end1)];
    int c1 = col[min(e + 8, end1)];
    for (int it = rounds - 1; it > 0; --it) {
      uint4 u0 = tlq[(size_t)c0 * 8 + l8];
      uint4 u1 = tlq[(size_t)c1 * 8 + l8];
      int en = e + 16;
      int cn0 = col[min(en, end1)];
      int cn1 = col[min(en + 8, end1)];
      acc8(a0, u0); acc8(a1, u1);
      c0 = cn0; c1 = cn1; e = en;
    }
    uint4 u0 = tlq[(size_t)c0 * 8 + l8];
    uint4 u1 = tlq[(size_t)c1 * 8 + l8];
    uint4 z = make_uint4(0u, 0u, 0u, 0u);
    if (e >= end) u0 = z;
    if (e + 8 >= end) u1 = z;
    acc8(a0, u0); acc8(a1, u1);
  }
  float v[8];
#pragma unroll
  for (int j = 0; j < 8; ++j) {
    float t = a0[j] + a1[j];
    t += __shfl_xor(t, 32);
    t += __shfl_xor(t, 16);
    t += __shfl_xor(t, 8);
    v[j] = t;
  }
  bool valid = l8 < 5;  // channels 8*l8..8*l8+7 < 40
  float di = 1.0f / (float)max(deg, 1);
  float4 r0 = valid ? *(const float4*)(tr + (size_t)n * 40 + 8 * l8)
                    : make_float4(0.f, 0.f, 0.f, 0.f);
  float4 r1 = valid ? *(const float4*)(tr + (size_t)n * 40 + 8 * l8 + 4)
                    : make_float4(0.f, 0.f, 0.f, 0.f);
  float rb[8] = {r0.x, r0.y, r0.z, r0.w, r1.x, r1.y, r1.z, r1.w};
  float vv[8];
#pragma unroll
  for (int j = 0; j < 8; ++j) vv[j] = valid ? fmaf(v[j], di, rb[j]) : -INFINITY;
  float m = vv[0];
#pragma unroll
  for (int j = 1; j < 8; ++j) m = fmaxf(m, vv[j]);
#pragma unroll
  for (int off = 4; off; off >>= 1) m = fmaxf(m, __shfl_xor(m, off));
  float ex = 0.f;
  if (valid) {
#pragma unroll
    for (int j = 0; j < 8; ++j) ex += expf(vv[j] - m);
  }
  float ssum = ex;
#pragma unroll
  for (int off = 4; off; off >>= 1) ssum += __shfl_xor(ssum, off);
  float lg = logf(ssum);
  if (ew == 0 && valid) {
    float4 o0, o1;
    o0.x = (vv[0] - m) - lg; o0.y = (vv[1] - m) - lg;
    o0.z = (vv[2] - m) - lg; o0.w = (vv[3] - m) - lg;
    o1.x = (vv[4] - m) - lg; o1.y = (vv[5] - m) - lg;
    o1.z = (vv[6] - m) - lg; o1.w = (vv[7] - m) - lg;
    *(float4*)(out + (size_t)n * 40 + 8 * l8) = o0;
    *(float4*)(out + (size_t)n * 40 + 8 * l8 + 4) = o1;
  }
}

// ---------------- launcher ----------------

extern "C" void kernel_launch(void* const* d_in, const int* in_sizes, int n_in,
                              void* d_out, int out_size, void* d_ws, size_t ws_size,
                              hipStream_t stream) {
  const float* x   = (const float*)d_in[0];
  const int*   ei  = (const int*)d_in[1];
  const float* Wl0 = (const float*)d_in[2];
  const float* Wr0 = (const float*)d_in[3];
  const float* b0  = (const float*)d_in[4];
  const float* Wl1 = (const float*)d_in[5];
  const float* Wr1 = (const float*)d_in[6];
  const float* b1  = (const float*)d_in[7];
  const float* Wl2 = (const float*)d_in[8];
  const float* Wr2 = (const float*)d_in[9];
  const float* b2  = (const float*)d_in[10];

  int N = in_sizes[0] / 128;
  int E = in_sizes[1] / 2;
  const int* src = ei;
  const int* dst = ei + E;
  int nbk = (N + BSIZE - 1) / BSIZE;       // 391 buckets of 256 nodes
  int chunk = (E + NEB - 1) / NEB;         // edges per hist/place block

  char* ws = (char*)d_ws;
  size_t off = 0;
  auto alloc = [&](size_t bytes) -> void* {
    void* p = ws + off;
    off += (bytes + 255) & ~(size_t)255;
    return p;
  };
  unsigned short* gA  = (unsigned short*)alloc((size_t)N * 128 * 2);
  unsigned short* gB  = (unsigned short*)alloc((size_t)N * 128 * 2);
  unsigned short* hC  = (unsigned short*)alloc((size_t)N * 128 * 2);
  unsigned short* tlb = (unsigned short*)alloc((size_t)N * 64 * 2);
  float* tr           = (float*)alloc((size_t)N * 40 * 4);
  int* row_ptr  = (int*)alloc((size_t)(N + 1) * 4);
  int* col      = (int*)alloc((size_t)E * 4);
  int* bedge    = (int*)alloc((size_t)E * 4);   // packed (src<<8)|(dst&255)
  int* cnt_bm   = (int*)alloc((size_t)NEB * nbk * 4);
  int* locoff   = (int*)alloc((size_t)nbk * NEB * 4);
  int* bktot    = (int*)alloc((size_t)nbk * 4);
  int* bbase    = (int*)alloc((size_t)(nbk + 1) * 4);
  unsigned short* wswz0 = (unsigned short*)alloc(32768 * 2);
  unsigned short* wswz1 = (unsigned short*)alloc(32768 * 2);
  unsigned short* wswz2 = (unsigned short*)alloc(10240 * 2);
  (void)ws_size; (void)n_in; (void)out_size;

  // CSR build (no global atomics; all writes block-local or exact-offset)
  k_ehist<<<NEB, 256, 0, stream>>>(dst, cnt_bm, E, chunk, nbk);
  k_bktscan<<<nbk, 256, 0, stream>>>(cnt_bm, locoff, bktot, nbk);
  k_topscan<<<1, 256, 0, stream>>>(bktot, bbase, nbk, E, row_ptr, N);
  k_eplace<<<NEB, 256, 0, stream>>>(src, dst, bbase, locoff, bedge, E, chunk, nbk);
  k_bcsr2<<<nbk, 256, 0, stream>>>(bedge, bbase, row_ptr, col, N);

  // weight swizzles (single dispatch for all 3 layers)
  k_wswz_all<<<296, 256, 0, stream>>>(Wl0, Wr0, Wl1, Wr1, Wl2, Wr2,
                                      wswz0, wswz1, wswz2);

  int gg128 = (N + 127) / 128;
  int gg = (N + 63) / 64;
  int nb = (N + 3) / 4;

  // layer 0 (reads fp32 X directly, converts in-register)
  gemm128_mfma_x32<<<gg128, 256, 0, stream>>>(x, wswz0, b0, gA, gB, N);
  agg128b<<<nb, 256, 0, stream>>>(gA, gB, row_ptr, col, hC, N);
  // layer 1
  gemm128_mfma<<<gg128, 256, 0, stream>>>(hC, wswz1, b1, gA, gB, N);
  agg128b<<<nb, 256, 0, stream>>>(gA, gB, row_ptr, col, hC, N);
  // layer 2 (40-dim) + log_softmax
  gemm40_mfma<<<gg, 256, 0, stream>>>(hC, wswz2, b2, tlb, tr, N);
  agg40_lsm<<<nb, 256, 0, stream>>>(tlb, tr, row_ptr, col, (float*)d_out, N);
}